// Round 1
// baseline (100526.434 us; speedup 1.0000x reference)
//
#include <hip/hip_runtime.h>

#define NSAMP 32768
#define INF 512
#define OUTF 512
#define NB 8            // spline bases per input (GRID_SIZE + SPLINE_ORDER)
#define KSP 4096        // INF * NB
#define KTOT 4608       // KSP + INF (silu columns)

typedef __attribute__((ext_vector_type(8))) short bf16x8;
typedef __attribute__((ext_vector_type(4))) short bf16x4;
typedef __attribute__((ext_vector_type(4))) float f32x4;

typedef __attribute__((address_space(1))) void gas_void;
typedef __attribute__((address_space(3))) void las_void;
#define GLL16(g, l) __builtin_amdgcn_global_load_lds( \
    (const gas_void*)(g), (las_void*)(l), 16, 0, 0)

// float -> bf16, round-nearest-even (inputs are finite; no NaN path needed)
__device__ __forceinline__ unsigned short f2bf(float f) {
  unsigned int u = __float_as_uint(f);
  u += 0x7fffu + ((u >> 16) & 1u);
  return (unsigned short)(u >> 16);
}

// Closed-form uniform cubic B-spline bases (grid: 12 knots, -6.6 step 1.2).
// Only 4 bases are nonzero: indices (c-3..c) clipped to [0,7], where c is the
// knot cell. Matches the reference Cox-de-Boor recursion on this uniform grid.
__device__ __forceinline__ void kan_feats(float xv, float b[NB], float* sil) {
  *sil = xv / (1.0f + __expf(-xv));
  float t = (xv + 6.6f) * (1.0f / 1.2f);
  float cf = floorf(t);
  int c = (int)cf;
  float u = (xv - (cf * 1.2f - 6.6f)) * (1.0f / 1.2f);
  float omu = 1.0f - u;
  float u2 = u * u, u3 = u2 * u;
  float w0 = (1.0f / 6.0f) * omu * omu * omu;
  float w1 = (1.0f / 6.0f) * (3.0f * u3 - 6.0f * u2 + 4.0f);
  float w2 = (1.0f / 6.0f) * (-3.0f * u3 + 3.0f * u2 + 3.0f * u + 1.0f);
  float w3 = (1.0f / 6.0f) * u3;
  int t0 = c - 3;
  #pragma unroll
  for (int j = 0; j < NB; ++j) {
    int m = j - t0;
    float v = (m == 0) ? w0 : (m == 1) ? w1 : (m == 2) ? w2 : (m == 3) ? w3 : 0.0f;
    b[j] = v;
  }
}

// W_aug[o][KTOT]: cols i*8+k = spline_weight[o,i,k]*scaler[o,i]; col 4096+i = base_weight[o,i]
__global__ __launch_bounds__(256) void kan_prep_w(
    const float* __restrict__ bw, const float* __restrict__ sw,
    const float* __restrict__ sc, unsigned short* __restrict__ W) {
  int idx = blockIdx.x * 256 + threadIdx.x;   // o*512 + i
  float scv = sc[idx];
  float4 s0 = ((const float4*)sw)[idx * 2 + 0];
  float4 s1 = ((const float4*)sw)[idx * 2 + 1];
  unsigned short v[8];
  v[0] = f2bf(s0.x * scv); v[1] = f2bf(s0.y * scv);
  v[2] = f2bf(s0.z * scv); v[3] = f2bf(s0.w * scv);
  v[4] = f2bf(s1.x * scv); v[5] = f2bf(s1.y * scv);
  v[6] = f2bf(s1.z * scv); v[7] = f2bf(s1.w * scv);
  int o = idx >> 9, i = idx & 511;
  *(bf16x8*)(W + (size_t)o * KTOT + i * NB) = *(bf16x8*)v;
  W[(size_t)o * KTOT + KSP + i] = f2bf(bw[idx]);
}

// A_aug[n][KTOT]: cols i*8+k = B_k(x[n,i]); col 4096+i = silu(x[n,i])
__global__ __launch_bounds__(256) void kan_prep_a(
    const float* __restrict__ x, unsigned short* __restrict__ A) {
  int idx = blockIdx.x * 256 + threadIdx.x;   // n*128 + i4
  int n = idx >> 7, i4 = idx & 127;
  float4 xv = ((const float4*)x)[idx];
  float xe[4] = {xv.x, xv.y, xv.z, xv.w};
  unsigned short sil[4];
  unsigned short* Arow = A + (size_t)n * KTOT;
  #pragma unroll
  for (int e = 0; e < 4; ++e) {
    float b[NB], s;
    kan_feats(xe[e], b, &s);
    unsigned short vb[NB];
    #pragma unroll
    for (int k = 0; k < NB; ++k) vb[k] = f2bf(b[k]);
    *(bf16x8*)(Arow + (i4 * 4 + e) * NB) = *(bf16x8*)vb;
    sil[e] = f2bf(s);
  }
  *(bf16x4*)(Arow + KSP + i4 * 4) = *(bf16x4*)sil;
}

// m97-structure GEMM: out[32768][512] = A_aug[32768][4608] @ W_aug[512][4608]^T
// 128x128 tile, BK=64, global_load_lds(16B) staging, 16x16x32 bf16 MFMA.
__global__ __launch_bounds__(256, 2) void kan_gemm(
    const unsigned short* __restrict__ A, const unsigned short* __restrict__ W,
    float* __restrict__ out) {
  __shared__ __align__(16) unsigned short As[128 * 64];
  __shared__ __align__(16) unsigned short Bs[128 * 64];
  const int tid = threadIdx.x;
  const int wave = tid >> 6;
  const int lane = tid & 63;
  const int frow = lane & 15;
  const int quad = lane >> 4;
  const int mtile = blockIdx.x >> 2;   // 4 column-tiles of one row-slab adjacent -> L3 reuse of A
  const int ntile = blockIdx.x & 3;
  const int wm = (wave & 1) << 6;
  const int wn = (wave >> 1) << 6;

  f32x4 acc[4][4];
  #pragma unroll
  for (int i = 0; i < 4; ++i)
    #pragma unroll
    for (int j = 0; j < 4; ++j)
      acc[i][j] = (f32x4){0.f, 0.f, 0.f, 0.f};

  // staging: each wave covers 32 rows; 8 lanes x 16B per row-segment of 128B
  const int srow = wave * 32 + (lane >> 3);
  const int scol = (lane & 7) * 8;
  const unsigned short* ag = A + ((size_t)mtile * 128 + srow) * KTOT + scol;
  const unsigned short* bg = W + (size_t)(ntile * 128 + srow) * KTOT + scol;

  for (int kc = 0; kc < KTOT / 64; ++kc) {
    const int k0 = kc * 64;
    #pragma unroll
    for (int is = 0; is < 4; ++is) {
      GLL16(ag + (size_t)is * 8 * KTOT + k0, &As[(wave * 32 + is * 8) * 64]);
      GLL16(bg + (size_t)is * 8 * KTOT + k0, &Bs[(wave * 32 + is * 8) * 64]);
    }
    __syncthreads();
    #pragma unroll
    for (int ks = 0; ks < 2; ++ks) {
      bf16x8 av[4], bv[4];
      #pragma unroll
      for (int f = 0; f < 4; ++f) {
        av[f] = *(const bf16x8*)&As[(wm + f * 16 + frow) * 64 + ks * 32 + quad * 8];
        bv[f] = *(const bf16x8*)&Bs[(wn + f * 16 + frow) * 64 + ks * 32 + quad * 8];
      }
      #pragma unroll
      for (int mf = 0; mf < 4; ++mf)
        #pragma unroll
        for (int nf = 0; nf < 4; ++nf)
          acc[mf][nf] = __builtin_amdgcn_mfma_f32_16x16x32_bf16(
              av[mf], bv[nf], acc[mf][nf], 0, 0, 0);
    }
    __syncthreads();
  }

  const size_t m0 = (size_t)mtile * 128;
  const int n0 = ntile * 128;
  #pragma unroll
  for (int mf = 0; mf < 4; ++mf)
    #pragma unroll
    for (int nf = 0; nf < 4; ++nf)
      #pragma unroll
      for (int r = 0; r < 4; ++r)
        out[(m0 + wm + mf * 16 + quad * 4 + r) * OUTF + (n0 + wn + nf * 16 + frow)] =
            acc[mf][nf][r];
}

// Correct-but-slow fp32 fallback if ws is too small for the materialized path.
__global__ __launch_bounds__(256) void kan_naive(
    const float* __restrict__ x, const float* __restrict__ bw,
    const float* __restrict__ sw, const float* __restrict__ sc,
    float* __restrict__ out) {
  int idx = blockIdx.x * 256 + threadIdx.x;   // n*512 + o
  int n = idx >> 9, o = idx & 511;
  const float* xr = x + (size_t)n * INF;
  float acc = 0.f;
  for (int i = 0; i < INF; ++i) {
    float b[NB], s;
    kan_feats(xr[i], b, &s);
    int wi = o * INF + i;
    acc += s * bw[wi];
    float sp = 0.f;
    #pragma unroll
    for (int k = 0; k < NB; ++k) sp += b[k] * sw[wi * NB + k];
    acc += sp * sc[wi];
  }
  out[idx] = acc;
}

extern "C" void kernel_launch(void* const* d_in, const int* in_sizes, int n_in,
                              void* d_out, int out_size, void* d_ws, size_t ws_size,
                              hipStream_t stream) {
  const float* x  = (const float*)d_in[0];
  const float* bw = (const float*)d_in[1];
  const float* sw = (const float*)d_in[2];
  const float* sc = (const float*)d_in[3];
  float* out = (float*)d_out;

  const size_t wbytes = (size_t)OUTF * KTOT * 2;    // 4.72 MB
  const size_t abytes = (size_t)NSAMP * KTOT * 2;   // 302 MB
  if (ws_size >= wbytes + abytes) {
    unsigned short* W  = (unsigned short*)d_ws;
    unsigned short* Aa = (unsigned short*)((char*)d_ws + wbytes);
    kan_prep_w<<<(OUTF * INF) / 256, 256, 0, stream>>>(bw, sw, sc, W);
    kan_prep_a<<<(NSAMP * (INF / 4)) / 256, 256, 0, stream>>>(x, Aa);
    kan_gemm<<<(NSAMP / 128) * (OUTF / 128), 256, 0, stream>>>(Aa, W, out);
  } else {
    kan_naive<<<(NSAMP * OUTF) / 256, 256, 0, stream>>>(x, bw, sw, sc, out);
  }
}

// Round 2
// 495.248 us; speedup vs baseline: 202.9822x; 202.9822x over previous
//
#include <hip/hip_runtime.h>

#define NSAMP 32768
#define INF 512
#define OUTF 512
#define NB 8            // spline bases per input
#define KSP 4096        // INF * NB (spline columns)
#define KTOT 4608       // KSP + INF (silu columns)

typedef __attribute__((ext_vector_type(8))) short bf16x8;
typedef __attribute__((ext_vector_type(4))) float f32x4;

typedef __attribute__((address_space(1))) void gas_void;
typedef __attribute__((address_space(3))) void las_void;
#define GLL16(g, l) __builtin_amdgcn_global_load_lds( \
    (const gas_void*)(g), (las_void*)(l), 16, 0, 0)

// float -> bf16, round-nearest-even (finite inputs)
__device__ __forceinline__ unsigned short f2bf(float f) {
  unsigned int u = __float_as_uint(f);
  u += 0x7fffu + ((u >> 16) & 1u);
  return (unsigned short)(u >> 16);
}

// W_aug[o][KTOT]: cols i*8+k = spline_weight[o,i,k]*scaler[o,i]; col 4096+i = base_weight[o,i]
__global__ __launch_bounds__(256) void kan_prep_w(
    const float* __restrict__ bw, const float* __restrict__ sw,
    const float* __restrict__ sc, unsigned short* __restrict__ W) {
  int idx = blockIdx.x * 256 + threadIdx.x;   // o*512 + i
  float scv = sc[idx];
  float4 s0 = ((const float4*)sw)[idx * 2 + 0];
  float4 s1 = ((const float4*)sw)[idx * 2 + 1];
  unsigned short v[8];
  v[0] = f2bf(s0.x * scv); v[1] = f2bf(s0.y * scv);
  v[2] = f2bf(s0.z * scv); v[3] = f2bf(s0.w * scv);
  v[4] = f2bf(s1.x * scv); v[5] = f2bf(s1.y * scv);
  v[6] = f2bf(s1.z * scv); v[7] = f2bf(s1.w * scv);
  int o = idx >> 9, i = idx & 511;
  *(bf16x8*)(W + (size_t)o * KTOT + i * NB) = *(bf16x8*)v;
  W[(size_t)o * KTOT + KSP + i] = f2bf(bw[idx]);
}

__device__ __forceinline__ void mfma_chunk(
    const unsigned short* As, const unsigned short* Bs,
    f32x4 acc[4][4], int wm, int wn, int frow, int quad) {
  #pragma unroll
  for (int ks = 0; ks < 2; ++ks) {
    bf16x8 av[4], bv[4];
    #pragma unroll
    for (int f = 0; f < 4; ++f) {
      av[f] = *(const bf16x8*)&As[(wm + f * 16 + frow) * 64 + ks * 32 + quad * 8];
      bv[f] = *(const bf16x8*)&Bs[(wn + f * 16 + frow) * 64 + ks * 32 + quad * 8];
    }
    #pragma unroll
    for (int mf = 0; mf < 4; ++mf)
      #pragma unroll
      for (int nf = 0; nf < 4; ++nf)
        acc[mf][nf] = __builtin_amdgcn_mfma_f32_16x16x32_bf16(
            av[mf], bv[nf], acc[mf][nf], 0, 0, 0);
  }
}

// Fused: out[32768][512] = A_aug(x) @ W_aug^T, A-tile computed on the fly in LDS.
// 64 spline chunks (8 inputs x 8 bases) then 8 silu chunks (64 inputs).
__global__ __launch_bounds__(256, 2) void kan_fused(
    const float* __restrict__ x, const unsigned short* __restrict__ W,
    float* __restrict__ out) {
  __shared__ __align__(16) unsigned short As[128 * 64];
  __shared__ __align__(16) unsigned short Bs[128 * 64];
  const int tid = threadIdx.x;
  const int wave = tid >> 6;
  const int lane = tid & 63;
  const int frow = lane & 15;
  const int quad = lane >> 4;
  const int lr = lane >> 3;     // row within 8-row group
  const int lc = lane & 7;      // input / column-segment within group
  const int mtile = blockIdx.x >> 2;   // 4 ntiles of one row-slab adjacent -> x reuse in L2/L3
  const int ntile = blockIdx.x & 3;
  const int wm = (wave & 1) << 6;
  const int wn = (wave >> 1) << 6;

  f32x4 acc[4][4];
  #pragma unroll
  for (int i = 0; i < 4; ++i)
    #pragma unroll
    for (int j = 0; j < 4; ++j)
      acc[i][j] = (f32x4){0.f, 0.f, 0.f, 0.f};

  // W staging: wave covers 32 rows; lane l -> row +l>>3, 16B segment (l&7)
  const unsigned short* bg =
      W + (size_t)(ntile * 128 + wave * 32 + lr) * KTOT + lc * 8;
  const float* xb = x + (size_t)mtile * 128 * INF;
  const bf16x8 zero8 = (bf16x8){0, 0, 0, 0, 0, 0, 0, 0};

  // ---- Phase 1: spline columns, 64 chunks of 8 inputs ----
  for (int kc = 0; kc < 64; ++kc) {
    #pragma unroll
    for (int is = 0; is < 4; ++is)
      GLL16(bg + (size_t)(is * 8) * KTOT + kc * 64, &Bs[(wave * 32 + is * 8) * 64]);

    // compute 8-basis slot for (row, input kc*8+lc); VALU work overlaps GLL flight
    #pragma unroll
    for (int is = 0; is < 4; ++is) {
      const int row = wave * 32 + is * 8 + lr;
      float xv = xb[(size_t)row * INF + kc * NB + lc];
      unsigned short* slot = &As[(row * NB + lc) * NB];
      *(bf16x8*)slot = zero8;
      float t = (xv + 6.6f) * (1.0f / 1.2f);
      float cf = floorf(t);
      float u = t - cf;
      int j0 = (int)cf - 3;     // first nonzero basis index (may be out of [0,8))
      float omu = 1.0f - u;
      float u2 = u * u, u3 = u2 * u;
      float w0 = (1.0f / 6.0f) * omu * omu * omu;
      float w1 = (1.0f / 6.0f) * (3.0f * u3 - 6.0f * u2 + 4.0f);
      float w2 = (1.0f / 6.0f) * (-3.0f * u3 + 3.0f * u2 + 3.0f * u + 1.0f);
      float w3 = (1.0f / 6.0f) * u3;
      if ((unsigned)j0 < 8u)       slot[j0]     = f2bf(w0);
      if ((unsigned)(j0 + 1) < 8u) slot[j0 + 1] = f2bf(w1);
      if ((unsigned)(j0 + 2) < 8u) slot[j0 + 2] = f2bf(w2);
      if ((unsigned)(j0 + 3) < 8u) slot[j0 + 3] = f2bf(w3);
    }
    __syncthreads();
    mfma_chunk(As, Bs, acc, wm, wn, frow, quad);
    __syncthreads();
  }

  // ---- Phase 2: silu columns, 8 chunks of 64 inputs ----
  for (int sc = 0; sc < 8; ++sc) {
    #pragma unroll
    for (int is = 0; is < 4; ++is)
      GLL16(bg + (size_t)(is * 8) * KTOT + KSP + sc * 64,
            &Bs[(wave * 32 + is * 8) * 64]);

    #pragma unroll
    for (int is = 0; is < 4; ++is) {
      const int row = wave * 32 + is * 8 + lr;
      const float* xr = xb + (size_t)row * INF + sc * 64 + lc * 8;
      float4 v0 = *(const float4*)xr;
      float4 v1 = *(const float4*)(xr + 4);
      float vv[8] = {v0.x, v0.y, v0.z, v0.w, v1.x, v1.y, v1.z, v1.w};
      unsigned short s[8];
      #pragma unroll
      for (int e = 0; e < 8; ++e) {
        float xe = vv[e];
        s[e] = f2bf(xe / (1.0f + __expf(-xe)));
      }
      *(bf16x8*)&As[row * 64 + lc * 8] = *(bf16x8*)s;
    }
    __syncthreads();
    mfma_chunk(As, Bs, acc, wm, wn, frow, quad);
    __syncthreads();
  }

  // ---- Epilogue ----
  const size_t m0 = (size_t)mtile * 128;
  const int n0 = ntile * 128;
  #pragma unroll
  for (int mf = 0; mf < 4; ++mf)
    #pragma unroll
    for (int nf = 0; nf < 4; ++nf)
      #pragma unroll
      for (int r = 0; r < 4; ++r)
        out[(m0 + wm + mf * 16 + quad * 4 + r) * OUTF + (n0 + wn + nf * 16 + frow)] =
            acc[mf][nf][r];
}

// Correct-but-slow fp32 fallback (only if ws can't even hold W_aug: 4.7 MB)
__global__ __launch_bounds__(256) void kan_naive(
    const float* __restrict__ x, const float* __restrict__ bw,
    const float* __restrict__ sw, const float* __restrict__ sc,
    float* __restrict__ out) {
  int idx = blockIdx.x * 256 + threadIdx.x;
  int n = idx >> 9, o = idx & 511;
  const float* xr = x + (size_t)n * INF;
  float acc = 0.f;
  for (int i = 0; i < INF; ++i) {
    float xv = xr[i];
    float sil = xv / (1.0f + __expf(-xv));
    float t = (xv + 6.6f) * (1.0f / 1.2f);
    float cf = floorf(t);
    float u = t - cf;
    int j0 = (int)cf - 3;
    float omu = 1.0f - u;
    float u2 = u * u, u3 = u2 * u;
    float w[4];
    w[0] = (1.0f / 6.0f) * omu * omu * omu;
    w[1] = (1.0f / 6.0f) * (3.0f * u3 - 6.0f * u2 + 4.0f);
    w[2] = (1.0f / 6.0f) * (-3.0f * u3 + 3.0f * u2 + 3.0f * u + 1.0f);
    w[3] = (1.0f / 6.0f) * u3;
    int wi = o * INF + i;
    acc += sil * bw[wi];
    float sp = 0.f;
    #pragma unroll
    for (int m = 0; m < 4; ++m) {
      int j = j0 + m;
      if ((unsigned)j < 8u) sp += w[m] * sw[wi * NB + j];
    }
    acc += sp * sc[wi];
  }
  out[idx] = acc;
}

extern "C" void kernel_launch(void* const* d_in, const int* in_sizes, int n_in,
                              void* d_out, int out_size, void* d_ws, size_t ws_size,
                              hipStream_t stream) {
  const float* x  = (const float*)d_in[0];
  const float* bw = (const float*)d_in[1];
  const float* sw = (const float*)d_in[2];
  const float* sc = (const float*)d_in[3];
  float* out = (float*)d_out;

  const size_t wbytes = (size_t)OUTF * KTOT * 2;    // 4.72 MB
  if (ws_size >= wbytes) {
    unsigned short* W = (unsigned short*)d_ws;
    kan_prep_w<<<(OUTF * INF) / 256, 256, 0, stream>>>(bw, sw, sc, W);
    kan_fused<<<(NSAMP / 128) * (OUTF / 128), 256, 0, stream>>>(x, W, out);
  } else {
    kan_naive<<<(NSAMP * OUTF) / 256, 256, 0, stream>>>(x, bw, sw, sc, out);
  }
}

// Round 3
// 318.416 us; speedup vs baseline: 315.7081x; 1.5553x over previous
//
#include <hip/hip_runtime.h>

#define NSAMP 32768
#define INF 512
#define OUTF 512
#define NB 8            // spline bases per input
#define KSP 4096        // INF * NB (spline columns)
#define KTOT 4608       // KSP + INF (silu columns)

typedef __attribute__((ext_vector_type(8))) short bf16x8;
typedef __attribute__((ext_vector_type(4))) float f32x4;

typedef __attribute__((address_space(1))) void gas_void;
typedef __attribute__((address_space(3))) void las_void;
#define GLL16(g, l) __builtin_amdgcn_global_load_lds( \
    (const gas_void*)(g), (las_void*)(l), 16, 0, 0)

// float -> bf16 round-nearest-even (for W prep; cheap, runs once)
__device__ __forceinline__ unsigned short f2bf(float f) {
  unsigned int u = __float_as_uint(f);
  u += 0x7fffu + ((u >> 16) & 1u);
  return (unsigned short)(u >> 16);
}

// pack two floats as bf16 pair (round-nearest-up: +0x8000 then take high half)
// result = [bf(hi) : bf(lo)], lo in low 16 bits.  One v_perm after the adds.
__device__ __forceinline__ unsigned pack_rn(float lo, float hi) {
  return __builtin_amdgcn_perm(__float_as_uint(hi) + 0x8000u,
                               __float_as_uint(lo) + 0x8000u, 0x07060302u);
}

// Full 8-slot cubic B-spline basis vector for x, as 4 dwords (8 bf16),
// computed branchlessly in registers. Grid: 12 knots, -6.6 step 1.2.
// Nonzero window w0..w3 at slots j0..j0+3, clipped to [0,8); out-of-grid -> 0.
__device__ __forceinline__ uint4 kan_basis_vec(float xv) {
  float t = __builtin_fmaf(xv, 1.0f / 1.2f, 5.5f);   // (x+6.6)/1.2
  float cf = floorf(t);
  float u = t - cf;
  int j0 = (int)cf - 3;
  float omu = 1.0f - u;
  float u2 = u * u, u3 = u2 * u;
  float w0 = (1.0f / 6.0f) * omu * omu * omu;
  float w1 = (1.0f / 6.0f) * (3.0f * u3 - 6.0f * u2 + 4.0f);
  float w2 = (1.0f / 6.0f) * (-3.0f * u3 + 3.0f * u2 + 3.0f * u + 1.0f);
  float w3 = (1.0f / 6.0f) * u3;
  unsigned P0 = pack_rn(w0, w1);     // halfwords [w0, w1]
  unsigned P1 = pack_rn(w2, w3);     // halfwords [w2, w3]
  // 128-bit value = P64 << (16*j0), bits outside [0,128) dropped.
  int p = j0 & 1;
  unsigned Q0 = p ? (P0 << 16) : P0;
  unsigned Q1 = p ? __builtin_amdgcn_alignbit(P1, P0, 16) : P1;
  unsigned Q2 = p ? (P1 >> 16) : 0u;
  int D = j0 >> 1;                   // arithmetic shift: floor(j0/2)
  uint4 r;
  r.x = (D == 0) ? Q0 : (D == -1) ? Q1 : (D == -2) ? Q2 : 0u;
  r.y = (D == 1) ? Q0 : (D ==  0) ? Q1 : (D == -1) ? Q2 : 0u;
  r.z = (D == 2) ? Q0 : (D ==  1) ? Q1 : (D ==  0) ? Q2 : 0u;
  r.w = (D == 3) ? Q0 : (D ==  2) ? Q1 : (D ==  1) ? Q2 : 0u;
  return r;
}

// W_aug[o][KTOT]: cols i*8+k = spline_weight[o,i,k]*scaler[o,i]; col 4096+i = base_weight[o,i]
__global__ __launch_bounds__(256) void kan_prep_w(
    const float* __restrict__ bw, const float* __restrict__ sw,
    const float* __restrict__ sc, unsigned short* __restrict__ W) {
  int idx = blockIdx.x * 256 + threadIdx.x;   // o*512 + i
  float scv = sc[idx];
  float4 s0 = ((const float4*)sw)[idx * 2 + 0];
  float4 s1 = ((const float4*)sw)[idx * 2 + 1];
  unsigned short v[8];
  v[0] = f2bf(s0.x * scv); v[1] = f2bf(s0.y * scv);
  v[2] = f2bf(s0.z * scv); v[3] = f2bf(s0.w * scv);
  v[4] = f2bf(s1.x * scv); v[5] = f2bf(s1.y * scv);
  v[6] = f2bf(s1.z * scv); v[7] = f2bf(s1.w * scv);
  int o = idx >> 9, i = idx & 511;
  *(bf16x8*)(W + (size_t)o * KTOT + i * NB) = *(bf16x8*)v;
  W[(size_t)o * KTOT + KSP + i] = f2bf(bw[idx]);
}

__device__ __forceinline__ void mfma_chunk(
    const unsigned short* As, const unsigned short* Bs,
    f32x4 acc[4][4], int wm, int wn, int frow, int quad) {
  #pragma unroll
  for (int ks = 0; ks < 2; ++ks) {
    bf16x8 av[4], bv[4];
    #pragma unroll
    for (int f = 0; f < 4; ++f) {
      av[f] = *(const bf16x8*)&As[(wm + f * 16 + frow) * 64 + ks * 32 + quad * 8];
      bv[f] = *(const bf16x8*)&Bs[(wn + f * 16 + frow) * 64 + ks * 32 + quad * 8];
    }
    #pragma unroll
    for (int mf = 0; mf < 4; ++mf)
      #pragma unroll
      for (int nf = 0; nf < 4; ++nf)
        acc[mf][nf] = __builtin_amdgcn_mfma_f32_16x16x32_bf16(
            av[mf], bv[nf], acc[mf][nf], 0, 0, 0);
  }
}

// Fused: out[32768][512] = A_aug(x) @ W_aug^T, A-tile computed on the fly.
// Basis vectors built fully in registers -> single conflict-free b128 LDS
// store per feature (no scatter, no zero-fill).
__global__ __launch_bounds__(256, 2) void kan_fused(
    const float* __restrict__ x, const unsigned short* __restrict__ W,
    float* __restrict__ out) {
  __shared__ __align__(16) unsigned short As[128 * 64];
  __shared__ __align__(16) unsigned short Bs[128 * 64];
  const int tid = threadIdx.x;
  const int wave = tid >> 6;
  const int lane = tid & 63;
  const int frow = lane & 15;
  const int quad = lane >> 4;
  const int lr = lane >> 3;     // row within 8-row group
  const int lc = lane & 7;      // input / 16B-segment within group
  const int mtile = blockIdx.x >> 2;   // 4 ntiles of one row-slab adjacent -> x/L2 reuse
  const int ntile = blockIdx.x & 3;
  const int wm = (wave & 1) << 6;
  const int wn = (wave >> 1) << 6;

  f32x4 acc[4][4];
  #pragma unroll
  for (int i = 0; i < 4; ++i)
    #pragma unroll
    for (int j = 0; j < 4; ++j)
      acc[i][j] = (f32x4){0.f, 0.f, 0.f, 0.f};

  // W staging: wave covers 32 rows; lane l -> row +(l>>3), 16B segment (l&7)
  const unsigned short* bg =
      W + (size_t)(ntile * 128 + wave * 32 + lr) * KTOT + lc * 8;
  const float* xb = x + (size_t)mtile * 128 * INF;

  // ---- Phase 1: spline columns, 64 chunks of 8 inputs ----
  for (int kc = 0; kc < 64; ++kc) {
    #pragma unroll
    for (int is = 0; is < 4; ++is)
      GLL16(bg + (size_t)(is * 8) * KTOT + kc * 64, &Bs[(wave * 32 + is * 8) * 64]);

    // thread (wave,lr,lc): basis vectors for rows wave*32+is*8+lr, input kc*8+lc
    float xv[4];
    #pragma unroll
    for (int is = 0; is < 4; ++is)
      xv[is] = xb[(size_t)(wave * 32 + is * 8 + lr) * INF + kc * 8 + lc];
    #pragma unroll
    for (int is = 0; is < 4; ++is) {
      const int row = wave * 32 + is * 8 + lr;
      uint4 bb = kan_basis_vec(xv[is]);
      *(uint4*)&As[row * 64 + lc * 8] = bb;   // 16B, lane-consecutive: conflict-free
    }
    __syncthreads();
    mfma_chunk(As, Bs, acc, wm, wn, frow, quad);
    __syncthreads();
  }

  // ---- Phase 2: silu columns, 8 chunks of 64 inputs ----
  for (int sc = 0; sc < 8; ++sc) {
    #pragma unroll
    for (int is = 0; is < 4; ++is)
      GLL16(bg + (size_t)(is * 8) * KTOT + KSP + sc * 64,
            &Bs[(wave * 32 + is * 8) * 64]);

    #pragma unroll
    for (int is = 0; is < 4; ++is) {
      const int row = wave * 32 + is * 8 + lr;
      const float* xr = xb + (size_t)row * INF + sc * 64 + lc * 8;
      float4 v0 = *(const float4*)xr;
      float4 v1 = *(const float4*)(xr + 4);
      float vv[8] = {v0.x, v0.y, v0.z, v0.w, v1.x, v1.y, v1.z, v1.w};
      float s[8];
      #pragma unroll
      for (int e = 0; e < 8; ++e)
        s[e] = vv[e] * __builtin_amdgcn_rcpf(1.0f + __expf(-vv[e]));
      uint4 pk;
      pk.x = pack_rn(s[0], s[1]);
      pk.y = pack_rn(s[2], s[3]);
      pk.z = pack_rn(s[4], s[5]);
      pk.w = pack_rn(s[6], s[7]);
      *(uint4*)&As[row * 64 + lc * 8] = pk;
    }
    __syncthreads();
    mfma_chunk(As, Bs, acc, wm, wn, frow, quad);
    __syncthreads();
  }

  // ---- Epilogue ----
  const size_t m0 = (size_t)mtile * 128;
  const int n0 = ntile * 128;
  #pragma unroll
  for (int mf = 0; mf < 4; ++mf)
    #pragma unroll
    for (int nf = 0; nf < 4; ++nf)
      #pragma unroll
      for (int r = 0; r < 4; ++r)
        out[(m0 + wm + mf * 16 + quad * 4 + r) * OUTF + (n0 + wn + nf * 16 + frow)] =
            acc[mf][nf][r];
}

// Correct-but-slow fp32 fallback (only if ws can't hold W_aug: 4.7 MB)
__global__ __launch_bounds__(256) void kan_naive(
    const float* __restrict__ x, const float* __restrict__ bw,
    const float* __restrict__ sw, const float* __restrict__ sc,
    float* __restrict__ out) {
  int idx = blockIdx.x * 256 + threadIdx.x;
  int n = idx >> 9, o = idx & 511;
  const float* xr = x + (size_t)n * INF;
  float acc = 0.f;
  for (int i = 0; i < INF; ++i) {
    float xv = xr[i];
    float sil = xv / (1.0f + __expf(-xv));
    float t = (xv + 6.6f) * (1.0f / 1.2f);
    float cf = floorf(t);
    float u = t - cf;
    int j0 = (int)cf - 3;
    float omu = 1.0f - u;
    float u2 = u * u, u3 = u2 * u;
    float w[4];
    w[0] = (1.0f / 6.0f) * omu * omu * omu;
    w[1] = (1.0f / 6.0f) * (3.0f * u3 - 6.0f * u2 + 4.0f);
    w[2] = (1.0f / 6.0f) * (-3.0f * u3 + 3.0f * u2 + 3.0f * u + 1.0f);
    w[3] = (1.0f / 6.0f) * u3;
    int wi = o * INF + i;
    acc += sil * bw[wi];
    float sp = 0.f;
    #pragma unroll
    for (int m = 0; m < 4; ++m) {
      int j = j0 + m;
      if ((unsigned)j < 8u) sp += w[m] * sw[wi * NB + j];
    }
    acc += sp * sc[wi];
  }
  out[idx] = acc;
}

extern "C" void kernel_launch(void* const* d_in, const int* in_sizes, int n_in,
                              void* d_out, int out_size, void* d_ws, size_t ws_size,
                              hipStream_t stream) {
  const float* x  = (const float*)d_in[0];
  const float* bw = (const float*)d_in[1];
  const float* sw = (const float*)d_in[2];
  const float* sc = (const float*)d_in[3];
  float* out = (float*)d_out;

  const size_t wbytes = (size_t)OUTF * KTOT * 2;    // 4.72 MB
  if (ws_size >= wbytes) {
    unsigned short* W = (unsigned short*)d_ws;
    kan_prep_w<<<(OUTF * INF) / 256, 256, 0, stream>>>(bw, sw, sc, W);
    kan_fused<<<(NSAMP / 128) * (OUTF / 128), 256, 0, stream>>>(x, W, out);
  } else {
    kan_naive<<<(NSAMP * OUTF) / 256, 256, 0, stream>>>(x, bw, sw, sc, out);
  }
}

// Round 4
// 294.190 us; speedup vs baseline: 341.7057x; 1.0823x over previous
//
#include <hip/hip_runtime.h>

#define NSAMP 32768
#define INF 512
#define OUTF 512
#define NB 8            // spline bases per input
#define KSP 4096        // INF * NB (spline columns)
#define KTOT 4608       // KSP + INF (silu columns)

typedef __attribute__((ext_vector_type(8))) short bf16x8;
typedef __attribute__((ext_vector_type(4))) float f32x4;

typedef __attribute__((address_space(1))) void gas_void;
typedef __attribute__((address_space(3))) void las_void;
#define GLL16(g, l) __builtin_amdgcn_global_load_lds( \
    (const gas_void*)(g), (las_void*)(l), 16, 0, 0)

// float -> bf16 round-nearest-even (W prep only)
__device__ __forceinline__ unsigned short f2bf(float f) {
  unsigned int u = __float_as_uint(f);
  u += 0x7fffu + ((u >> 16) & 1u);
  return (unsigned short)(u >> 16);
}

// pack two floats as bf16 pair (round-nearest-up). lo in low 16 bits.
__device__ __forceinline__ unsigned pack_rn(float lo, float hi) {
  return __builtin_amdgcn_perm(__float_as_uint(hi) + 0x8000u,
                               __float_as_uint(lo) + 0x8000u, 0x07060302u);
}

// Full 8-slot cubic B-spline basis vector for x as 4 dwords (8 bf16),
// branchless. Grid: knots 1.2j-3, j=-3..8; basis k support s in [k,k+4),
// s = (x+6.6)/1.2. Out-of-grid x -> all-zero (matches reference clipping).
__device__ __forceinline__ uint4 kan_basis_vec(float xv) {
  float t = __builtin_fmaf(xv, 1.0f / 1.2f, 5.5f);
  float cf = floorf(t);
  float u = t - cf;
  int j0 = (int)cf - 3;
  float omu = 1.0f - u;
  float u2 = u * u, u3 = u2 * u;
  float w0 = (1.0f / 6.0f) * omu * omu * omu;
  float w1 = (1.0f / 6.0f) * (3.0f * u3 - 6.0f * u2 + 4.0f);
  float w2 = (1.0f / 6.0f) * (-3.0f * u3 + 3.0f * u2 + 3.0f * u + 1.0f);
  float w3 = (1.0f / 6.0f) * u3;
  unsigned P0 = pack_rn(w0, w1);
  unsigned P1 = pack_rn(w2, w3);
  // 128-bit result = [P1:P0] << (16*j0), bits outside [0,128) dropped.
  int p = j0 & 1;
  unsigned Q0 = p ? (P0 << 16) : P0;
  unsigned Q1 = p ? __builtin_amdgcn_alignbit(P1, P0, 16) : P1;
  unsigned Q2 = p ? (P1 >> 16) : 0u;
  int D = j0 >> 1;
  uint4 r;
  r.x = (D == 0) ? Q0 : (D == -1) ? Q1 : (D == -2) ? Q2 : 0u;
  r.y = (D == 1) ? Q0 : (D ==  0) ? Q1 : (D == -1) ? Q2 : 0u;
  r.z = (D == 2) ? Q0 : (D ==  1) ? Q1 : (D ==  0) ? Q2 : 0u;
  r.w = (D == 3) ? Q0 : (D ==  2) ? Q1 : (D ==  1) ? Q2 : 0u;
  return r;
}

// W_aug[o][KTOT]: cols i*8+k = spline_weight[o,i,k]*scaler[o,i]; col 4096+i = base_weight[o,i]
__global__ __launch_bounds__(256) void kan_prep_w(
    const float* __restrict__ bw, const float* __restrict__ sw,
    const float* __restrict__ sc, unsigned short* __restrict__ W) {
  int idx = blockIdx.x * 256 + threadIdx.x;   // o*512 + i
  float scv = sc[idx];
  float4 s0 = ((const float4*)sw)[idx * 2 + 0];
  float4 s1 = ((const float4*)sw)[idx * 2 + 1];
  unsigned short v[8];
  v[0] = f2bf(s0.x * scv); v[1] = f2bf(s0.y * scv);
  v[2] = f2bf(s0.z * scv); v[3] = f2bf(s0.w * scv);
  v[4] = f2bf(s1.x * scv); v[5] = f2bf(s1.y * scv);
  v[6] = f2bf(s1.z * scv); v[7] = f2bf(s1.w * scv);
  int o = idx >> 9, i = idx & 511;
  *(bf16x8*)(W + (size_t)o * KTOT + i * NB) = *(bf16x8*)v;
  W[(size_t)o * KTOT + KSP + i] = f2bf(bw[idx]);
}

// Fragment compute on the XOR-swizzled LDS layout:
// element (row, seg s) lives at seg s^(row&7). Reads are 2-way max (free).
__device__ __forceinline__ void mfma_chunk(
    const unsigned short* As, const unsigned short* Bs,
    f32x4 acc[4][4], int wm, int wn, int frow, int quad) {
  const int fr7 = frow & 7;
  #pragma unroll
  for (int ks = 0; ks < 2; ++ks) {
    bf16x8 av[4], bv[4];
    const int sa = ((ks * 4 + quad) ^ fr7) * 8;
    #pragma unroll
    for (int f = 0; f < 4; ++f) {
      av[f] = *(const bf16x8*)&As[(wm + f * 16 + frow) * 64 + sa];
      bv[f] = *(const bf16x8*)&Bs[(wn + f * 16 + frow) * 64 + sa];
    }
    #pragma unroll
    for (int mf = 0; mf < 4; ++mf)
      #pragma unroll
      for (int nf = 0; nf < 4; ++nf)
        acc[mf][nf] = __builtin_amdgcn_mfma_f32_16x16x32_bf16(
            av[mf], bv[nf], acc[mf][nf], 0, 0, 0);
  }
}

// Fused out = A_aug(x) @ W_aug^T. A-tile computed on the fly in registers,
// one conflict-free b128 store per feature into swizzled LDS.
__global__ __launch_bounds__(256, 4) void kan_fused(
    const float* __restrict__ x, const unsigned short* __restrict__ W,
    float* __restrict__ out) {
  __shared__ __align__(16) unsigned short As[128 * 64];
  __shared__ __align__(16) unsigned short Bs[128 * 64];
  const int tid = threadIdx.x;
  const int wave = tid >> 6;
  const int lane = tid & 63;
  const int frow = lane & 15;
  const int quad = lane >> 4;
  const int lr = lane >> 3;     // row within 8-row group
  const int lc = lane & 7;      // 16B-segment / input within group
  // ntile-siblings 256 apart -> same XCD (round-robin %8) -> x shared in L2
  const int mtile = blockIdx.x & 255;
  const int ntile = blockIdx.x >> 8;
  const int wm = (wave & 1) << 6;
  const int wn = (wave >> 1) << 6;

  f32x4 acc[4][4];
  #pragma unroll
  for (int i = 0; i < 4; ++i)
    #pragma unroll
    for (int j = 0; j < 4; ++j)
      acc[i][j] = (f32x4){0.f, 0.f, 0.f, 0.f};

  // B staging pointers (one per 8-row group). Source seg XORed by lr so the
  // lane-linear GLL16 deposit lands swizzled in LDS. Advance 64 cols/chunk;
  // after 64 chunks they point exactly at the silu columns (KSP).
  const unsigned short* bgp[4];
  #pragma unroll
  for (int is = 0; is < 4; ++is)
    bgp[is] = W + (size_t)(ntile * 128 + wave * 32 + is * 8 + lr) * KTOT +
              ((lc ^ lr) * 8);
  const float* xb = x + (size_t)mtile * 128 * INF;
  const float* xp[4];
  #pragma unroll
  for (int is = 0; is < 4; ++is)
    xp[is] = xb + (size_t)(wave * 32 + is * 8 + lr) * INF + lc;

  // ---- Phase 1: spline columns, 64 chunks of 8 inputs ----
  float xc[4];
  #pragma unroll
  for (int is = 0; is < 4; ++is) xc[is] = xp[is][0];

  for (int kc = 0; kc < 64; ++kc) {
    #pragma unroll
    for (int is = 0; is < 4; ++is) {
      GLL16(bgp[is], &Bs[(wave * 32 + is * 8) * 64]);
      bgp[is] += 64;
    }
    // prefetch next chunk's x (wraps harmlessly on last iter)
    float xn[4];
    const int knext = ((kc + 1) & 63) * 8;
    #pragma unroll
    for (int is = 0; is < 4; ++is) xn[is] = xp[is][knext];

    #pragma unroll
    for (int is = 0; is < 4; ++is) {
      const int row = wave * 32 + is * 8 + lr;
      uint4 bb = kan_basis_vec(xc[is]);
      *(uint4*)&As[row * 64 + ((lc ^ lr) * 8)] = bb;   // swizzled, conflict-free
    }
    __syncthreads();
    mfma_chunk(As, Bs, acc, wm, wn, frow, quad);
    __syncthreads();
    #pragma unroll
    for (int is = 0; is < 4; ++is) xc[is] = xn[is];
  }

  // ---- Phase 2: silu columns, 8 chunks of 64 inputs ----
  for (int sc = 0; sc < 8; ++sc) {
    // issue x loads first so their wait isn't queued behind the GLLs
    float4 v0[4], v1[4];
    #pragma unroll
    for (int is = 0; is < 4; ++is) {
      const int row = wave * 32 + is * 8 + lr;
      const float* xr = xb + (size_t)row * INF + sc * 64 + lc * 8;
      v0[is] = *(const float4*)xr;
      v1[is] = *(const float4*)(xr + 4);
    }
    #pragma unroll
    for (int is = 0; is < 4; ++is) {
      GLL16(bgp[is], &Bs[(wave * 32 + is * 8) * 64]);
      bgp[is] += 64;
    }
    #pragma unroll
    for (int is = 0; is < 4; ++is) {
      const int row = wave * 32 + is * 8 + lr;
      float vv[8] = {v0[is].x, v0[is].y, v0[is].z, v0[is].w,
                     v1[is].x, v1[is].y, v1[is].z, v1[is].w};
      float s[8];
      #pragma unroll
      for (int e = 0; e < 8; ++e)
        s[e] = vv[e] * __builtin_amdgcn_rcpf(1.0f + __expf(-vv[e]));
      uint4 pk;
      pk.x = pack_rn(s[0], s[1]);
      pk.y = pack_rn(s[2], s[3]);
      pk.z = pack_rn(s[4], s[5]);
      pk.w = pack_rn(s[6], s[7]);
      *(uint4*)&As[row * 64 + ((lc ^ lr) * 8)] = pk;
    }
    __syncthreads();
    mfma_chunk(As, Bs, acc, wm, wn, frow, quad);
    __syncthreads();
  }

  // ---- Epilogue ----
  const size_t m0 = (size_t)mtile * 128;
  const int n0 = ntile * 128;
  #pragma unroll
  for (int mf = 0; mf < 4; ++mf)
    #pragma unroll
    for (int nf = 0; nf < 4; ++nf)
      #pragma unroll
      for (int r = 0; r < 4; ++r)
        out[(m0 + wm + mf * 16 + quad * 4 + r) * OUTF + (n0 + wn + nf * 16 + frow)] =
            acc[mf][nf][r];
}

// Correct-but-slow fp32 fallback (only if ws can't hold W_aug: 4.7 MB)
__global__ __launch_bounds__(256) void kan_naive(
    const float* __restrict__ x, const float* __restrict__ bw,
    const float* __restrict__ sw, const float* __restrict__ sc,
    float* __restrict__ out) {
  int idx = blockIdx.x * 256 + threadIdx.x;
  int n = idx >> 9, o = idx & 511;
  const float* xr = x + (size_t)n * INF;
  float acc = 0.f;
  for (int i = 0; i < INF; ++i) {
    float xv = xr[i];
    float sil = xv / (1.0f + __expf(-xv));
    float t = (xv + 6.6f) * (1.0f / 1.2f);
    float cf = floorf(t);
    float u = t - cf;
    int j0 = (int)cf - 3;
    float omu = 1.0f - u;
    float u2 = u * u, u3 = u2 * u;
    float w[4];
    w[0] = (1.0f / 6.0f) * omu * omu * omu;
    w[1] = (1.0f / 6.0f) * (3.0f * u3 - 6.0f * u2 + 4.0f);
    w[2] = (1.0f / 6.0f) * (-3.0f * u3 + 3.0f * u2 + 3.0f * u + 1.0f);
    w[3] = (1.0f / 6.0f) * u3;
    int wi = o * INF + i;
    acc += sil * bw[wi];
    float sp = 0.f;
    #pragma unroll
    for (int m = 0; m < 4; ++m) {
      int j = j0 + m;
      if ((unsigned)j < 8u) sp += w[m] * sw[wi * NB + j];
    }
    acc += sp * sc[wi];
  }
  out[idx] = acc;
}

extern "C" void kernel_launch(void* const* d_in, const int* in_sizes, int n_in,
                              void* d_out, int out_size, void* d_ws, size_t ws_size,
                              hipStream_t stream) {
  const float* x  = (const float*)d_in[0];
  const float* bw = (const float*)d_in[1];
  const float* sw = (const float*)d_in[2];
  const float* sc = (const float*)d_in[3];
  float* out = (float*)d_out;

  const size_t wbytes = (size_t)OUTF * KTOT * 2;    // 4.72 MB
  if (ws_size >= wbytes) {
    unsigned short* W = (unsigned short*)d_ws;
    kan_prep_w<<<(OUTF * INF) / 256, 256, 0, stream>>>(bw, sw, sc, W);
    kan_fused<<<(NSAMP / 128) * (OUTF / 128), 256, 0, stream>>>(x, W, out);
  } else {
    kan_naive<<<(NSAMP * OUTF) / 256, 256, 0, stream>>>(x, bw, sw, sc, out);
  }
}

// Round 5
// 247.949 us; speedup vs baseline: 405.4322x; 1.1865x over previous
//
#include <hip/hip_runtime.h>

#define NSAMP 32768
#define INF 512
#define OUTF 512
#define NB 8            // spline bases per input
#define KSP 4096        // INF * NB (spline columns)
#define KTOT 4608       // KSP + INF (silu columns)

typedef __attribute__((ext_vector_type(8))) short bf16x8;
typedef __attribute__((ext_vector_type(4))) float f32x4;

typedef __attribute__((address_space(1))) void gas_void;
typedef __attribute__((address_space(3))) void las_void;
#define GLL16(g, l) __builtin_amdgcn_global_load_lds( \
    (const gas_void*)(g), (las_void*)(l), 16, 0, 0)

// float -> bf16 round-nearest-even (W prep only)
__device__ __forceinline__ unsigned short f2bf(float f) {
  unsigned int u = __float_as_uint(f);
  u += 0x7fffu + ((u >> 16) & 1u);
  return (unsigned short)(u >> 16);
}

// pack two floats as bf16 pair (round-nearest-up). lo in low 16 bits.
__device__ __forceinline__ unsigned pack_rn(float lo, float hi) {
  return __builtin_amdgcn_perm(__float_as_uint(hi) + 0x8000u,
                               __float_as_uint(lo) + 0x8000u, 0x07060302u);
}

// 8-slot cubic B-spline basis vector, scaled by 6 (the 1/6 is folded into W).
// Branchless; out-of-grid x -> all-zero (matches reference clipping).
__device__ __forceinline__ uint4 kan_basis_vec(float xv) {
  float t = __builtin_fmaf(xv, 1.0f / 1.2f, 5.5f);   // (x+6.6)/1.2
  float cf = floorf(t);
  float u = t - cf;
  int j0 = (int)cf - 3;
  float omu = 1.0f - u;
  float u2 = u * u, u3 = u2 * u;
  float omu2 = omu * omu;
  float w0 = omu2 * omu;                                         // 6*(1/6)omu^3
  float w1 = __builtin_fmaf(3.f, u3, __builtin_fmaf(-6.f, u2, 4.f));
  float w2 = __builtin_fmaf(-3.f, u3,
              __builtin_fmaf(3.f, u2, __builtin_fmaf(3.f, u, 1.f)));
  float w3 = u3;
  unsigned P0 = pack_rn(w0, w1);
  unsigned P1 = pack_rn(w2, w3);
  // 128-bit result = [P1:P0] << (16*j0), bits outside [0,128) dropped.
  int p = j0 & 1;
  unsigned Q0 = p ? (P0 << 16) : P0;
  unsigned Q1 = p ? __builtin_amdgcn_alignbit(P1, P0, 16) : P1;
  unsigned Q2 = p ? (P1 >> 16) : 0u;
  int D = j0 >> 1;
  uint4 r;
  r.x = (D == 0) ? Q0 : (D == -1) ? Q1 : (D == -2) ? Q2 : 0u;
  r.y = (D == 1) ? Q0 : (D ==  0) ? Q1 : (D == -1) ? Q2 : 0u;
  r.z = (D == 2) ? Q0 : (D ==  1) ? Q1 : (D ==  0) ? Q2 : 0u;
  r.w = (D == 3) ? Q0 : (D ==  2) ? Q1 : (D ==  1) ? Q2 : 0u;
  return r;
}

// W_aug[o][KTOT]: cols i*8+k = spline_weight[o,i,k]*scaler[o,i]/6 (basis is 6w);
// col 4096+i = base_weight[o,i]
__global__ __launch_bounds__(256) void kan_prep_w(
    const float* __restrict__ bw, const float* __restrict__ sw,
    const float* __restrict__ sc, unsigned short* __restrict__ W) {
  int idx = blockIdx.x * 256 + threadIdx.x;   // o*512 + i
  float scv = sc[idx] * (1.0f / 6.0f);
  float4 s0 = ((const float4*)sw)[idx * 2 + 0];
  float4 s1 = ((const float4*)sw)[idx * 2 + 1];
  unsigned short v[8];
  v[0] = f2bf(s0.x * scv); v[1] = f2bf(s0.y * scv);
  v[2] = f2bf(s0.z * scv); v[3] = f2bf(s0.w * scv);
  v[4] = f2bf(s1.x * scv); v[5] = f2bf(s1.y * scv);
  v[6] = f2bf(s1.z * scv); v[7] = f2bf(s1.w * scv);
  int o = idx >> 9, i = idx & 511;
  *(bf16x8*)(W + (size_t)o * KTOT + i * NB) = *(bf16x8*)v;
  W[(size_t)o * KTOT + KSP + i] = f2bf(bw[idx]);
}

// Fragment compute on the XOR-swizzled layout: element (row, seg s) lives at
// seg s^(row&7). 64x128 per wave: av[4] x bv[8].
__device__ __forceinline__ void mfma_chunk(
    const unsigned short* As, const unsigned short* Bs,
    f32x4 acc[4][8], int wm, int wn, int frow, int quad) {
  const int fr7 = frow & 7;
  #pragma unroll
  for (int ks = 0; ks < 2; ++ks) {
    bf16x8 av[4], bv[8];
    const int sa = ((ks * 4 + quad) ^ fr7) * 8;
    #pragma unroll
    for (int f = 0; f < 4; ++f)
      av[f] = *(const bf16x8*)&As[(wm + f * 16 + frow) * 64 + sa];
    #pragma unroll
    for (int g = 0; g < 8; ++g)
      bv[g] = *(const bf16x8*)&Bs[(wn + g * 16 + frow) * 64 + sa];
    #pragma unroll
    for (int mf = 0; mf < 4; ++mf)
      #pragma unroll
      for (int nf = 0; nf < 8; ++nf)
        acc[mf][nf] = __builtin_amdgcn_mfma_f32_16x16x32_bf16(
            av[mf], bv[nf], acc[mf][nf], 0, 0, 0);
  }
}

// Fused out = A_aug(x) @ W_aug^T. 128(M) x 256(N) tile per 256-thread block:
// basis vectors serve 2x the output columns of the R4 kernel.
__global__ __launch_bounds__(256, 2) void kan_fused(
    const float* __restrict__ x, const unsigned short* __restrict__ W,
    float* __restrict__ out) {
  __shared__ __align__(16) unsigned short As[128 * 64];   // 16 KB
  __shared__ __align__(16) unsigned short Bs[256 * 64];   // 32 KB
  const int tid = threadIdx.x;
  const int wave = tid >> 6;
  const int lane = tid & 63;
  const int frow = lane & 15;
  const int quad = lane >> 4;
  const int lr = lane >> 3;     // row within 8-row group
  const int lc = lane & 7;      // 16B-segment / input within group
  // ntile-siblings 256 apart -> same XCD (round-robin %8) -> x shared in L2
  const int mtile = blockIdx.x & 255;
  const int ntile = blockIdx.x >> 8;          // 0..1
  const int wm = (wave & 1) << 6;
  const int wn = (wave >> 1) << 7;            // 0 or 128

  f32x4 acc[4][8];
  #pragma unroll
  for (int i = 0; i < 4; ++i)
    #pragma unroll
    for (int j = 0; j < 8; ++j)
      acc[i][j] = (f32x4){0.f, 0.f, 0.f, 0.f};

  // B staging: wave covers 64 rows (8 groups of 8). Source seg XORed by lr so
  // the lane-linear GLL16 deposit lands swizzled. +64 cols/chunk; after 64
  // chunks pointers sit exactly at the silu columns (KSP).
  const unsigned short* bgp[8];
  #pragma unroll
  for (int is = 0; is < 8; ++is)
    bgp[is] = W + (size_t)(ntile * 256 + wave * 64 + is * 8 + lr) * KTOT +
              ((lc ^ lr) * 8);
  const float* xb = x + (size_t)mtile * 128 * INF;
  const float* xp[4];
  #pragma unroll
  for (int is = 0; is < 4; ++is)
    xp[is] = xb + (size_t)(wave * 32 + is * 8 + lr) * INF + lc;

  // ---- Phase 1: spline columns, 64 chunks of 8 inputs ----
  float xc[4];
  #pragma unroll
  for (int is = 0; is < 4; ++is) xc[is] = xp[is][0];

  for (int kc = 0; kc < 64; ++kc) {
    #pragma unroll
    for (int is = 0; is < 8; ++is) {
      GLL16(bgp[is], &Bs[(wave * 64 + is * 8) * 64]);
      bgp[is] += 64;
    }
    // prefetch next chunk's x (wraps harmlessly on last iter)
    float xn[4];
    const int knext = ((kc + 1) & 63) * 8;
    #pragma unroll
    for (int is = 0; is < 4; ++is) xn[is] = xp[is][knext];

    #pragma unroll
    for (int is = 0; is < 4; ++is) {
      const int row = wave * 32 + is * 8 + lr;
      uint4 bb = kan_basis_vec(xc[is]);
      *(uint4*)&As[row * 64 + ((lc ^ lr) * 8)] = bb;   // swizzled, conflict-free
    }
    __syncthreads();
    mfma_chunk(As, Bs, acc, wm, wn, frow, quad);
    __syncthreads();
    #pragma unroll
    for (int is = 0; is < 4; ++is) xc[is] = xn[is];
  }

  // ---- Phase 2: silu columns, 8 chunks of 64 inputs ----
  for (int sc = 0; sc < 8; ++sc) {
    float4 v0[4], v1[4];
    #pragma unroll
    for (int is = 0; is < 4; ++is) {
      const int row = wave * 32 + is * 8 + lr;
      const float* xr = xb + (size_t)row * INF + sc * 64 + lc * 8;
      v0[is] = *(const float4*)xr;
      v1[is] = *(const float4*)(xr + 4);
    }
    #pragma unroll
    for (int is = 0; is < 8; ++is) {
      GLL16(bgp[is], &Bs[(wave * 64 + is * 8) * 64]);
      bgp[is] += 64;
    }
    #pragma unroll
    for (int is = 0; is < 4; ++is) {
      const int row = wave * 32 + is * 8 + lr;
      float vv[8] = {v0[is].x, v0[is].y, v0[is].z, v0[is].w,
                     v1[is].x, v1[is].y, v1[is].z, v1[is].w};
      float s[8];
      #pragma unroll
      for (int e = 0; e < 8; ++e)
        s[e] = vv[e] * __builtin_amdgcn_rcpf(1.0f + __expf(-vv[e]));
      uint4 pk;
      pk.x = pack_rn(s[0], s[1]);
      pk.y = pack_rn(s[2], s[3]);
      pk.z = pack_rn(s[4], s[5]);
      pk.w = pack_rn(s[6], s[7]);
      *(uint4*)&As[row * 64 + ((lc ^ lr) * 8)] = pk;
    }
    __syncthreads();
    mfma_chunk(As, Bs, acc, wm, wn, frow, quad);
    __syncthreads();
  }

  // ---- Epilogue ----
  const size_t m0 = (size_t)mtile * 128;
  const int n0 = ntile * 256;
  #pragma unroll
  for (int mf = 0; mf < 4; ++mf)
    #pragma unroll
    for (int nf = 0; nf < 8; ++nf)
      #pragma unroll
      for (int r = 0; r < 4; ++r)
        out[(m0 + wm + mf * 16 + quad * 4 + r) * OUTF + (n0 + wn + nf * 16 + frow)] =
            acc[mf][nf][r];
}

// Correct-but-slow fp32 fallback (only if ws can't hold W_aug: 4.7 MB)
__global__ __launch_bounds__(256) void kan_naive(
    const float* __restrict__ x, const float* __restrict__ bw,
    const float* __restrict__ sw, const float* __restrict__ sc,
    float* __restrict__ out) {
  int idx = blockIdx.x * 256 + threadIdx.x;
  int n = idx >> 9, o = idx & 511;
  const float* xr = x + (size_t)n * INF;
  float acc = 0.f;
  for (int i = 0; i < INF; ++i) {
    float xv = xr[i];
    float sil = xv / (1.0f + __expf(-xv));
    float t = (xv + 6.6f) * (1.0f / 1.2f);
    float cf = floorf(t);
    float u = t - cf;
    int j0 = (int)cf - 3;
    float omu = 1.0f - u;
    float u2 = u * u, u3 = u2 * u;
    float w[4];
    w[0] = (1.0f / 6.0f) * omu * omu * omu;
    w[1] = (1.0f / 6.0f) * (3.0f * u3 - 6.0f * u2 + 4.0f);
    w[2] = (1.0f / 6.0f) * (-3.0f * u3 + 3.0f * u2 + 3.0f * u + 1.0f);
    w[3] = (1.0f / 6.0f) * u3;
    int wi = o * INF + i;
    acc += sil * bw[wi];
    float sp = 0.f;
    #pragma unroll
    for (int m = 0; m < 4; ++m) {
      int j = j0 + m;
      if ((unsigned)j < 8u) sp += w[m] * sw[wi * NB + j];
    }
    acc += sp * sc[wi];
  }
  out[idx] = acc;
}

extern "C" void kernel_launch(void* const* d_in, const int* in_sizes, int n_in,
                              void* d_out, int out_size, void* d_ws, size_t ws_size,
                              hipStream_t stream) {
  const float* x  = (const float*)d_in[0];
  const float* bw = (const float*)d_in[1];
  const float* sw = (const float*)d_in[2];
  const float* sc = (const float*)d_in[3];
  float* out = (float*)d_out;

  const size_t wbytes = (size_t)OUTF * KTOT * 2;    // 4.72 MB
  if (ws_size >= wbytes) {
    unsigned short* W = (unsigned short*)d_ws;
    kan_prep_w<<<(OUTF * INF) / 256, 256, 0, stream>>>(bw, sw, sc, W);
    kan_fused<<<(NSAMP / 128) * (OUTF / 256), 256, 0, stream>>>(x, W, out);
  } else {
    kan_naive<<<(NSAMP * OUTF) / 256, 256, 0, stream>>>(x, bw, sw, sc, out);
  }
}